// Round 6
// baseline (3441.656 us; speedup 1.0000x reference)
//
#include <hip/hip_runtime.h>

// CustomFourierLayer: out[b,o] = sum_{i,k} coef[o,i,k] * f_k(x[b,i])
// R6: barrier-free, LDS-free GEMM. Each lane generates its own A-fragment
// harmonics in registers (row = lane&31, harmonic group = lane>>5), B is
// loaded global->VGPR in fragment order 1 substep ahead. No __syncthreads
// in the K-loop => no vmcnt/lgkmcnt drains; pure dataflow scheduling.
// Wave tile 64x128 (fr=2, fc=4), block = 4 waves = 256 rows x 128 cols,
// grid 512 (kb-outer for XCD L2 locality), split-K x4, partials epilogue.

#define O_COLS 1024
#define I_DIM  1024
#define NF33   33
#define B_ROWS 4096

#define CW2_BYTES  ((size_t)32 * 2048 * 512 * 2)   // 64 MiB, f16 frag blobs
#define XT_OFF     (CW2_BYTES)                      // 16 MiB f32 x^T
#define XT_BYTES   ((size_t)I_DIM * B_ROWS * 4)
#define BK_OFF     (XT_OFF + XT_BYTES)              // 4 MiB f32 bk32[i][o]
#define BK_BYTES   ((size_t)I_DIM * O_COLS * 4)
#define BIAS_OFF   (BK_OFF + BK_BYTES)              // 4 KiB
#define PART_OFF   (BIAS_OFF + (1 << 20))           // 3 x 16 MiB partials
#define PART_BYTES ((size_t)B_ROWS * O_COLS * 4)
#define NEED_T1    (PART_OFF + 3 * PART_BYTES)
#define NEED_T2    (BIAS_OFF + 4096)

typedef _Float16 half8 __attribute__((ext_vector_type(8)));
typedef float f32x16 __attribute__((ext_vector_type(16)));
typedef float float4v __attribute__((ext_vector_type(4)));
union H8 { half8 v; _Float16 h[8]; };

// source k in coef's [sin1..16 | cos1..16 | 1] layout for interleaved feature f
__device__ __forceinline__ int ksrc_of(int f) {
  return (f >= 32) ? 32 : ((f >> 1) + ((f & 1) ? 16 : 0));
}

// ---------------------------------------------------------------------------
// coef f32 [o][i][k] -> Cw2 f16 in 32x32x16 B-fragment blobs + bk32[i][o]=k32.
// Blob (ob32, i*2+kcl) = 1KB: lane l = kh*32 + (o&31) holds 8 f16 = features
// kcl*16 + kh*8 + e of column i, output col o = ob32*32 + (l&31).
// ---------------------------------------------------------------------------
__global__ __launch_bounds__(256)
void convert_coef2(const float* __restrict__ coef, _Float16* __restrict__ Cw2,
                   float* __restrict__ bk) {
  const int gtid = blockIdx.x * 256 + threadIdx.x;   // 1M threads
  const int o = gtid & 1023;
  const int i = gtid >> 10;

  const float* src = coef + (size_t)o * (I_DIM * NF33) + (size_t)i * NF33;
  float r[NF33];
#pragma unroll
  for (int k = 0; k < NF33; ++k) r[k] = src[k];

  const int ob32 = o >> 5;
#pragma unroll
  for (int kcl = 0; kcl < 2; ++kcl) {
#pragma unroll
    for (int kh = 0; kh < 2; ++kh) {
      H8 h;
#pragma unroll
      for (int e = 0; e < 8; ++e)
        h.h[e] = (_Float16)r[ksrc_of(kcl * 16 + kh * 8 + e)];
      const size_t blob = (size_t)ob32 * 2048 + (size_t)i * 2 + kcl;
      *(half8*)(Cw2 + blob * 512 + (kh * 32 + (o & 31)) * 8) = h.v;
    }
  }
  bk[(size_t)i * 1024 + o] = r[32];
}

// x [4096][1024] -> xT [1024][4096]
__global__ __launch_bounds__(256)
void transpose_x(const float* __restrict__ x, float* __restrict__ xT) {
  __shared__ float t[64][65];
  const int bi = blockIdx.x;   // I-tile 0..15
  const int bj = blockIdx.y;   // B-tile 0..63
  const int tx = threadIdx.x & 63, ty = threadIdx.x >> 6;
#pragma unroll
  for (int mq = 0; mq < 16; ++mq) {
    const int r = mq * 4 + ty;
    t[r][tx] = x[(size_t)(bj * 64 + r) * I_DIM + bi * 64 + tx];
  }
  __syncthreads();
#pragma unroll
  for (int mq = 0; mq < 16; ++mq) {
    const int r = mq * 4 + ty;
    xT[(size_t)(bi * 64 + r) * B_ROWS + bj * 64 + tx] = t[tx][r];
  }
}

// bias[o] = sum_i bk[i][o]
__global__ __launch_bounds__(256)
void bias_from_bk(const float* __restrict__ bk, float* __restrict__ bias) {
  const int o = blockIdx.x * 256 + threadIdx.x;
  float s0 = 0.f, s1 = 0.f, s2 = 0.f, s3 = 0.f;
  for (int i = 0; i < 1024; i += 4) {
    s0 += bk[(size_t)i * 1024 + o];
    s1 += bk[(size_t)(i + 1) * 1024 + o];
    s2 += bk[(size_t)(i + 2) * 1024 + o];
    s3 += bk[(size_t)(i + 3) * 1024 + o];
  }
  bias[o] = (s0 + s1) + (s2 + s3);
}

// out += p0 + p1 + p2
__global__ __launch_bounds__(256)
void reduce_parts(float* __restrict__ out, const float* __restrict__ p0,
                  const float* __restrict__ p1, const float* __restrict__ p2) {
  const size_t i = ((size_t)blockIdx.x * 256 + threadIdx.x) * 4;
  float4v a = *(float4v*)(out + i);
  float4v b = *(const float4v*)(p0 + i);
  float4v c = *(const float4v*)(p1 + i);
  float4v d = *(const float4v*)(p2 + i);
  *(float4v*)(out + i) = a + b + c + d;
}

// ---------------------------------------------------------------------------
// Barrier-free GEMM. 256 threads = 4 waves; wave w owns rows
// m0 + w*64 .. +64 (fr=2 frags of 32) and cols o0..o0+127 (fc=4).
// Substep = one i-column (32 features = kcl 0,1). B prefetched 1 ahead.
// ---------------------------------------------------------------------------
template <bool ATOMIC>
__global__ __launch_bounds__(256, 2)
void fourier_gemm4(const float* __restrict__ xT, const _Float16* __restrict__ Cw2,
                   const float* __restrict__ bias, float* __restrict__ out,
                   float* __restrict__ part) {
  const int tid = threadIdx.x, lane = tid & 63, wave = tid >> 6;
  const int bid = blockIdx.x;           // bid = kb*128 + m*8 + n
  const int n = bid & 7;                // col-tile == XCD slot
  const int m = (bid >> 3) & 15;
  const int kb = bid >> 7;              // 0..3
  const int o0 = n * 128;
  const int m0 = m * 256;
  const int r32 = lane & 31, kh = lane >> 5;
  const int rowA = m0 + wave * 64 + r32;          // fr=0 row; fr=1 is +32

  const float kA = (float)(4 * kh + 1);           // base harmonic of this lane

  // 4 col-blob pointers (advance 1 KB per substep)
  const _Float16* pb0 = Cw2 + ((size_t)(n * 4) * 2048 + (size_t)kb * 512) * 512 + lane * 8;
  const _Float16* pb1 = pb0 + (size_t)2048 * 512;
  const _Float16* pb2 = pb0 + (size_t)2 * 2048 * 512;
  const _Float16* pb3 = pb0 + (size_t)3 * 2048 * 512;

  const float* px = xT + (size_t)(kb * 256) * B_ROWS + rowA;

  f32x16 acc[2][4];
#pragma unroll
  for (int fr = 0; fr < 2; ++fr)
#pragma unroll
    for (int fc = 0; fc < 4; ++fc)
#pragma unroll
      for (int q = 0; q < 16; ++q) acc[fr][fc][q] = 0.f;
  if (kb == 0) {
#pragma unroll
    for (int fc = 0; fc < 4; ++fc) {
      const float bv = bias[o0 + fc * 32 + r32];
#pragma unroll
      for (int fr = 0; fr < 2; ++fr)
#pragma unroll
        for (int q = 0; q < 16; ++q) acc[fr][fc][q] = bv;
    }
  }

  auto loadB = [&](half8 (&Bt)[8]) {
    Bt[0] = *(const half8*)(pb0); Bt[1] = *(const half8*)(pb0 + 512);
    Bt[2] = *(const half8*)(pb1); Bt[3] = *(const half8*)(pb1 + 512);
    Bt[4] = *(const half8*)(pb2); Bt[5] = *(const half8*)(pb2 + 512);
    Bt[6] = *(const half8*)(pb3); Bt[7] = *(const half8*)(pb3 + 512);
    pb0 += 1024; pb1 += 1024; pb2 += 1024; pb3 += 1024;
  };

  // per-lane A-fragments for one x value: f0 = harmonics kA..kA+3 (kcl=0),
  // f1 = harmonics kA+8..kA+11 (kcl=1); [sin,cos] interleaved, RNE f16.
  auto frags_of = [&](float xv, half8& f0, half8& f1) {
    float s1, c1, sa, ca;
    __sincosf(xv, &s1, &c1);
    __sincosf(kA * xv, &sa, &ca);
    H8 h0, h1;
    float s = sa, c = ca;
    h0.h[0] = (_Float16)s; h0.h[1] = (_Float16)c;
#pragma unroll
    for (int q = 1; q < 4; ++q) {
      const float ns = s * c1 + c * s1;
      c = c * c1 - s * s1; s = ns;
      h0.h[2 * q] = (_Float16)s; h0.h[2 * q + 1] = (_Float16)c;
    }
    const float s2 = 2.f * s1 * c1, c2 = 2.f * c1 * c1 - 1.f;
    const float s4 = 2.f * s2 * c2, c4 = 2.f * c2 * c2 - 1.f;
    const float s8 = 2.f * s4 * c4, c8 = 2.f * c4 * c4 - 1.f;
    s = sa * c8 + ca * s8; c = ca * c8 - sa * s8;
    h1.h[0] = (_Float16)s; h1.h[1] = (_Float16)c;
#pragma unroll
    for (int q = 1; q < 4; ++q) {
      const float ns = s * c1 + c * s1;
      c = c * c1 - s * s1; s = ns;
      h1.h[2 * q] = (_Float16)s; h1.h[2 * q + 1] = (_Float16)c;
    }
    f0 = h0.v; f1 = h1.v;
  };

  auto step = [&](half8 (&Bu)[8], float xA, float xB) {
    half8 a[2][2];
    frags_of(xA, a[0][0], a[0][1]);
    frags_of(xB, a[1][0], a[1][1]);
    __builtin_amdgcn_s_setprio(1);
#pragma unroll
    for (int kcl = 0; kcl < 2; ++kcl)
#pragma unroll
      for (int fr = 0; fr < 2; ++fr)
#pragma unroll
        for (int fc = 0; fc < 4; ++fc)
          acc[fr][fc] = __builtin_amdgcn_mfma_f32_32x32x16_f16(
              a[fr][kcl], Bu[fc * 2 + kcl], acc[fr][fc], 0, 0, 0);
    __builtin_amdgcn_s_setprio(0);
  };

  half8 Bc[8];
  loadB(Bc);
  float xAc = px[0], xBc = px[32];
  px += B_ROWS;

#pragma unroll 2
  for (int s = 0; s < 256; ++s) {
    if (s < 255) {
      half8 Bn[8];
      loadB(Bn);
      const float xAn = px[0], xBn = px[32];
      px += B_ROWS;
      step(Bc, xAc, xBc);
#pragma unroll
      for (int q8 = 0; q8 < 8; ++q8) Bc[q8] = Bn[q8];
      xAc = xAn; xBc = xBn;
    } else {
      step(Bc, xAc, xBc);
    }
  }

  // epilogue: C/D 32x32 layout col=lane&31, row=(q&3)+8*(q>>2)+4*(lane>>5)
  float* dst;
  if (ATOMIC) dst = out;
  else dst = (kb == 0) ? out : part + (size_t)(kb - 1) * (B_ROWS * O_COLS);
#pragma unroll
  for (int fr = 0; fr < 2; ++fr)
#pragma unroll
    for (int fc = 0; fc < 4; ++fc)
#pragma unroll
      for (int q = 0; q < 16; ++q) {
        const int row = m0 + wave * 64 + fr * 32 + (q & 3) + 8 * (q >> 2) + 4 * kh;
        const int col = o0 + fc * 32 + r32;
        if (ATOMIC) atomicAdd(&dst[(size_t)row * O_COLS + col], acc[fr][fc][q]);
        else dst[(size_t)row * O_COLS + col] = acc[fr][fc][q];
      }
}

// ---------------------------------------------------------------------------
// Fallback (ws too small): direct-coef 16x16x32 path (no workspace).
// ---------------------------------------------------------------------------
__global__ __launch_bounds__(512, 4)
void fourier_gemm_direct(const float* __restrict__ x, const float* __restrict__ coef,
                         float* __restrict__ out) {
  __shared__ _Float16 Asd[128 * 64];
  __shared__ _Float16 Bsd[128 * 64];

  const int tid = threadIdx.x;
  const int lane = tid & 63;
  const int wave = tid >> 6;
  const int wr = wave >> 1;
  const int wc = wave & 1;

  const int bid = blockIdx.x;
  const int o0 = (bid & 7) * 128;
  const int kb = (bid >> 3) & 1;
  const int m0 = (bid >> 4) * 128;

  const int rowA = tid >> 3;
  const int cch = tid & 7;
  const int cswz = cch ^ (rowA & 7);
  const int n1 = tid >> 3;
  const int c1q = tid & 7;
  const int r16 = lane & 15;
  const int kq = lane >> 4;

  float4v acc[2][4];
#pragma unroll
  for (int fr = 0; fr < 2; ++fr)
#pragma unroll
    for (int fc = 0; fc < 4; ++fc) acc[fr][fc] = (float4v){0.f, 0.f, 0.f, 0.f};

  float s1a[8], c1a[8], sa[8], ca[8];
  float s1b[8], c1b[8], sb[8], cb[8];

  const float* xa_base = x + (size_t)(m0 + rowA) * I_DIM + (size_t)kb * 512 + cch * 8;
  const float* xb_base = xa_base + (size_t)64 * I_DIM;

#pragma unroll 1
  for (int ib2 = 0; ib2 < 8; ++ib2) {
    {
      const float* xa = xa_base + ib2 * 64;
      const float* xb = xb_base + ib2 * 64;
      float xva[8], xvb[8];
      *(float4*)&xva[0] = *(const float4*)(xa);
      *(float4*)&xva[4] = *(const float4*)(xa + 4);
      *(float4*)&xvb[0] = *(const float4*)(xb);
      *(float4*)&xvb[4] = *(const float4*)(xb + 4);
#pragma unroll
      for (int e = 0; e < 8; ++e) {
        __sincosf(xva[e], &s1a[e], &c1a[e]); sa[e] = s1a[e]; ca[e] = c1a[e];
        __sincosf(xvb[e], &s1b[e], &c1b[e]); sb[e] = s1b[e]; cb[e] = c1b[e];
      }
    }
#pragma unroll 1
    for (int f = 0; f < NF33; ++f) {
      H8 ha, hb;
      if (f == 32) {
#pragma unroll
        for (int e = 0; e < 8; ++e) { ha.h[e] = (_Float16)1.0f; hb.h[e] = (_Float16)1.0f; }
      } else if ((f & 1) == 0) {
#pragma unroll
        for (int e = 0; e < 8; ++e) { ha.h[e] = (_Float16)sa[e]; hb.h[e] = (_Float16)sb[e]; }
      } else {
#pragma unroll
        for (int e = 0; e < 8; ++e) { ha.h[e] = (_Float16)ca[e]; hb.h[e] = (_Float16)cb[e]; }
      }
      __syncthreads();
      {
        const int ks = ksrc_of(f);
        const int ibg = kb * 8 + ib2;
        H8 b1, b2;
#pragma unroll
        for (int e = 0; e < 8; ++e) {
          const size_t ii = (size_t)(ibg * 64 + c1q * 8 + e) * NF33 + ks;
          b1.h[e] = (_Float16)coef[(size_t)(o0 + n1) * (I_DIM * NF33) + ii];
          b2.h[e] = (_Float16)coef[(size_t)(o0 + n1 + 64) * (I_DIM * NF33) + ii];
        }
        const int cs = (c1q ^ (n1 & 7)) << 3;
        *(half8*)&Bsd[n1 * 64 + cs] = b1.v;
        *(half8*)&Bsd[(n1 + 64) * 64 + cs] = b2.v;
      }
      *(half8*)&Asd[rowA * 64 + cswz * 8] = ha.v;
      *(half8*)&Asd[(rowA + 64) * 64 + cswz * 8] = hb.v;
      if ((f & 1) && (f + 2 < NF33)) {
#pragma unroll
        for (int e = 0; e < 8; ++e) {
          float ns = sa[e] * c1a[e] + ca[e] * s1a[e];
          ca[e] = ca[e] * c1a[e] - sa[e] * s1a[e]; sa[e] = ns;
          float nsb = sb[e] * c1b[e] + cb[e] * s1b[e];
          cb[e] = cb[e] * c1b[e] - sb[e] * s1b[e]; sb[e] = nsb;
        }
      }
      __syncthreads();
#pragma unroll
      for (int ksu = 0; ksu < 2; ++ksu) {
        const int ch = ((ksu << 2) + kq) ^ (r16 & 7);
        half8 af[2], bf[4];
#pragma unroll
        for (int fr = 0; fr < 2; ++fr)
          af[fr] = *(const half8*)&Asd[(wr * 32 + fr * 16 + r16) * 64 + ch * 8];
#pragma unroll
        for (int fc = 0; fc < 4; ++fc)
          bf[fc] = *(const half8*)&Bsd[(wc * 64 + fc * 16 + r16) * 64 + ch * 8];
#pragma unroll
        for (int fr = 0; fr < 2; ++fr)
#pragma unroll
          for (int fc = 0; fc < 4; ++fc)
            acc[fr][fc] = __builtin_amdgcn_mfma_f32_16x16x32_f16(
                af[fr], bf[fc], acc[fr][fc], 0, 0, 0);
      }
    }
  }
#pragma unroll
  for (int fr = 0; fr < 2; ++fr)
#pragma unroll
    for (int fc = 0; fc < 4; ++fc)
#pragma unroll
      for (int r = 0; r < 4; ++r) {
        const int row = m0 + wr * 32 + fr * 16 + kq * 4 + r;
        const int col = o0 + wc * 64 + fc * 16 + r16;
        atomicAdd(&out[(size_t)row * O_COLS + col], acc[fr][fc][r]);
      }
}

extern "C" void kernel_launch(void* const* d_in, const int* in_sizes, int n_in,
                              void* d_out, int out_size, void* d_ws, size_t ws_size,
                              hipStream_t stream) {
  const float* x = (const float*)d_in[0];
  const float* coef = (const float*)d_in[1];
  float* out = (float*)d_out;

  if (ws_size >= NEED_T1 || ws_size >= NEED_T2) {
    _Float16* Cw2 = (_Float16*)d_ws;
    float* xT   = (float*)((char*)d_ws + XT_OFF);
    float* bk   = (float*)((char*)d_ws + BK_OFF);
    float* bias = (float*)((char*)d_ws + BIAS_OFF);
    convert_coef2<<<dim3(4096), dim3(256), 0, stream>>>(coef, Cw2, bk);
    transpose_x<<<dim3(16, 64), dim3(256), 0, stream>>>(x, xT);
    bias_from_bk<<<dim3(4), dim3(256), 0, stream>>>(bk, bias);
    if (ws_size >= NEED_T1) {
      float* part = (float*)((char*)d_ws + PART_OFF);
      fourier_gemm4<false><<<dim3(512), dim3(256), 0, stream>>>(xT, Cw2, bias, out, part);
      reduce_parts<<<dim3(4096), dim3(256), 0, stream>>>(
          out, part, part + (size_t)B_ROWS * O_COLS, part + (size_t)2 * B_ROWS * O_COLS);
    } else {
      hipMemsetAsync(out, 0, (size_t)B_ROWS * O_COLS * sizeof(float), stream);
      fourier_gemm4<true><<<dim3(512), dim3(256), 0, stream>>>(xT, Cw2, bias, out, nullptr);
    }
  } else {
    hipMemsetAsync(out, 0, (size_t)B_ROWS * O_COLS * sizeof(float), stream);
    fourier_gemm_direct<<<dim3(512), dim3(512), 0, stream>>>(x, coef, out);
  }
}

// Round 7
// 595.439 us; speedup vs baseline: 5.7800x; 5.7800x over previous
//
#include <hip/hip_runtime.h>

// CustomFourierLayer: out[b,o] = sum_{i,k} coef[o,i,k] * f_k(x[b,i])
// R7: hybrid of R5+R6 lessons. B shared via LDS (1 global_load_lds per
// thread per substep, double-buffered, one __syncthreads per substep);
// A generated per-lane in registers (no A LDS, no spill: acc only 64 VGPR);
// BM=256 BN=128, 8 waves of 64x64 (fr=2,fc=2), split-K x4, grid 512,
// __launch_bounds__(512,4) -> 16 waves/CU (2 blocks).

#define O_COLS 1024
#define I_DIM  1024
#define NF33   33
#define B_ROWS 4096

#define CW2_BYTES  ((size_t)32 * 2048 * 512 * 2)   // 64 MiB, f16 frag blobs
#define XT_OFF     (CW2_BYTES)                      // 16 MiB f32 x^T
#define XT_BYTES   ((size_t)I_DIM * B_ROWS * 4)
#define BK_OFF     (XT_OFF + XT_BYTES)              // 4 MiB f32 bk32[i][o]
#define BK_BYTES   ((size_t)I_DIM * O_COLS * 4)
#define BIAS_OFF   (BK_OFF + BK_BYTES)              // 4 KiB
#define PART_OFF   (BIAS_OFF + (1 << 20))           // 3 x 16 MiB partials
#define PART_BYTES ((size_t)B_ROWS * O_COLS * 4)
#define NEED_T1    (PART_OFF + 3 * PART_BYTES)
#define NEED_T2    (BIAS_OFF + 4096)

typedef _Float16 half8 __attribute__((ext_vector_type(8)));
typedef float f32x16 __attribute__((ext_vector_type(16)));
typedef float float4v __attribute__((ext_vector_type(4)));
union H8 { half8 v; _Float16 h[8]; };

__device__ __forceinline__ void gload16(const void* g, void* l) {
  typedef const __attribute__((address_space(1))) unsigned int GU;
  typedef __attribute__((address_space(3))) unsigned int LU;
  __builtin_amdgcn_global_load_lds((GU*)g, (LU*)l, 16, 0, 0);
}

// source k in coef's [sin1..16 | cos1..16 | 1] layout for interleaved feature f
__device__ __forceinline__ int ksrc_of(int f) {
  return (f >= 32) ? 32 : ((f >> 1) + ((f & 1) ? 16 : 0));
}

// ---------------------------------------------------------------------------
// coef f32 [o][i][k] -> Cw2 f16 in 32x32x16 B-fragment blobs + bk32[i][o]=k32.
// Blob (ob32, i*2+kcl) = 1KB: lane l = kh*32 + (o&31) holds 8 f16 = features
// kcl*16 + kh*8 + e of column i, output col o = ob32*32 + (l&31).
// (validated: R6 passed with this layout)
// ---------------------------------------------------------------------------
__global__ __launch_bounds__(256)
void convert_coef2(const float* __restrict__ coef, _Float16* __restrict__ Cw2,
                   float* __restrict__ bk) {
  const int gtid = blockIdx.x * 256 + threadIdx.x;   // 1M threads
  const int o = gtid & 1023;
  const int i = gtid >> 10;

  const float* src = coef + (size_t)o * (I_DIM * NF33) + (size_t)i * NF33;
  float r[NF33];
#pragma unroll
  for (int k = 0; k < NF33; ++k) r[k] = src[k];

  const int ob32 = o >> 5;
#pragma unroll
  for (int kcl = 0; kcl < 2; ++kcl) {
#pragma unroll
    for (int kh = 0; kh < 2; ++kh) {
      H8 h;
#pragma unroll
      for (int e = 0; e < 8; ++e)
        h.h[e] = (_Float16)r[ksrc_of(kcl * 16 + kh * 8 + e)];
      const size_t blob = (size_t)ob32 * 2048 + (size_t)i * 2 + kcl;
      *(half8*)(Cw2 + blob * 512 + (kh * 32 + (o & 31)) * 8) = h.v;
    }
  }
  bk[(size_t)i * 1024 + o] = r[32];
}

// x [4096][1024] -> xT [1024][4096]
__global__ __launch_bounds__(256)
void transpose_x(const float* __restrict__ x, float* __restrict__ xT) {
  __shared__ float t[64][65];
  const int bi = blockIdx.x;   // I-tile 0..15
  const int bj = blockIdx.y;   // B-tile 0..63
  const int tx = threadIdx.x & 63, ty = threadIdx.x >> 6;
#pragma unroll
  for (int mq = 0; mq < 16; ++mq) {
    const int r = mq * 4 + ty;
    t[r][tx] = x[(size_t)(bj * 64 + r) * I_DIM + bi * 64 + tx];
  }
  __syncthreads();
#pragma unroll
  for (int mq = 0; mq < 16; ++mq) {
    const int r = mq * 4 + ty;
    xT[(size_t)(bi * 64 + r) * B_ROWS + bj * 64 + tx] = t[tx][r];
  }
}

// bias[o] = sum_i bk[i][o]
__global__ __launch_bounds__(256)
void bias_from_bk(const float* __restrict__ bk, float* __restrict__ bias) {
  const int o = blockIdx.x * 256 + threadIdx.x;
  float s0 = 0.f, s1 = 0.f, s2 = 0.f, s3 = 0.f;
  for (int i = 0; i < 1024; i += 4) {
    s0 += bk[(size_t)i * 1024 + o];
    s1 += bk[(size_t)(i + 1) * 1024 + o];
    s2 += bk[(size_t)(i + 2) * 1024 + o];
    s3 += bk[(size_t)(i + 3) * 1024 + o];
  }
  bias[o] = (s0 + s1) + (s2 + s3);
}

// out += p0 + p1 + p2
__global__ __launch_bounds__(256)
void reduce_parts(float* __restrict__ out, const float* __restrict__ p0,
                  const float* __restrict__ p1, const float* __restrict__ p2) {
  const size_t i = ((size_t)blockIdx.x * 256 + threadIdx.x) * 4;
  float4v a = *(float4v*)(out + i);
  float4v b = *(const float4v*)(p0 + i);
  float4v c = *(const float4v*)(p1 + i);
  float4v d = *(const float4v*)(p2 + i);
  *(float4v*)(out + i) = a + b + c + d;
}

// ---------------------------------------------------------------------------
// GEMM: 512 threads = 8 waves (4 row-groups x 2 col-groups), wave 64x64
// (fr=2, fc=2). BM=256, BN=128. Substep = 1 i-column (32 features).
// B: Cw2 frag-blobs -> LDS via 1 gload16/thread (wave w copies blob
// (w>>1, kcl=w&1)), double-buffered; A: per-lane in-register harmonics.
// ---------------------------------------------------------------------------
template <bool ATOMIC>
__global__ __launch_bounds__(512, 4)
void fourier_gemm5(const float* __restrict__ xT, const _Float16* __restrict__ Cw2,
                   const float* __restrict__ bias, float* __restrict__ out,
                   float* __restrict__ part) {
  __shared__ _Float16 Bs[2][4096];   // 2 x 8 KB

  const int tid = threadIdx.x, lane = tid & 63, wave = tid >> 6;
  const int wr = wave >> 1;          // 0..3 : rows wr*64..+64
  const int wcl = wave & 1;          // 0..1 : cols wcl*64..+64

  const int bid = blockIdx.x;        // 512 = 8 n x 16 m x 4 kb
  const int n = bid & 7;             // col-tile == XCD slot
  const int m = (bid >> 3) & 15;
  const int kb = bid >> 7;           // 0..3 (256 i-cols each)
  const int o0 = n * 128;
  const int m0 = m * 256;
  const int i0 = kb * 256;

  const int r32 = lane & 31, kh = lane >> 5;
  const float kA = (float)(4 * kh + 1);

  // B staging: wave copies blob (ob32_local = wave>>1, kcl = wave&1)
  const _Float16* Bsrc = Cw2
      + ((size_t)(n * 4 + (wave >> 1)) * 2048 + (size_t)i0 * 2 + (wave & 1)) * 512
      + lane * 8;

  const float* px = xT + (size_t)i0 * B_ROWS + (m0 + wr * 64 + r32);

  f32x16 acc[2][2];
#pragma unroll
  for (int fr = 0; fr < 2; ++fr)
#pragma unroll
    for (int fc = 0; fc < 2; ++fc)
#pragma unroll
      for (int q = 0; q < 16; ++q) acc[fr][fc][q] = 0.f;
  if (kb == 0) {
#pragma unroll
    for (int fc = 0; fc < 2; ++fc) {
      const float bv = bias[o0 + wcl * 64 + fc * 32 + r32];
#pragma unroll
      for (int fr = 0; fr < 2; ++fr)
#pragma unroll
        for (int q = 0; q < 16; ++q) acc[fr][fc][q] = bv;
    }
  }

  // per-lane A-frags for one x: f0 = harmonics kA..kA+3 (kcl=0),
  // f1 = harmonics kA+8..kA+11 (kcl=1). (validated in R6)
  auto frags_of = [&](float xv, half8& f0, half8& f1) {
    float s1, c1, sa, ca;
    __sincosf(xv, &s1, &c1);
    __sincosf(kA * xv, &sa, &ca);
    H8 h0, h1;
    float s = sa, c = ca;
    h0.h[0] = (_Float16)s; h0.h[1] = (_Float16)c;
#pragma unroll
    for (int q = 1; q < 4; ++q) {
      const float ns = s * c1 + c * s1;
      c = c * c1 - s * s1; s = ns;
      h0.h[2 * q] = (_Float16)s; h0.h[2 * q + 1] = (_Float16)c;
    }
    const float s2 = 2.f * s1 * c1, c2 = 2.f * c1 * c1 - 1.f;
    const float s4 = 2.f * s2 * c2, c4 = 2.f * c2 * c2 - 1.f;
    const float s8 = 2.f * s4 * c4, c8 = 2.f * c4 * c4 - 1.f;
    s = sa * c8 + ca * s8; c = ca * c8 - sa * s8;
    h1.h[0] = (_Float16)s; h1.h[1] = (_Float16)c;
#pragma unroll
    for (int q = 1; q < 4; ++q) {
      const float ns = s * c1 + c * s1;
      c = c * c1 - s * s1; s = ns;
      h1.h[2 * q] = (_Float16)s; h1.h[2 * q + 1] = (_Float16)c;
    }
    f0 = h0.v; f1 = h1.v;
  };

  auto stage = [&](int pn, int s) {
    gload16(Bsrc + (size_t)s * 1024, (char*)&Bs[pn][0] + wave * 1024);
  };

  auto compute = [&](int pn, float xa, float xb) {
    half8 b[2][2];
#pragma unroll
    for (int fc = 0; fc < 2; ++fc)
#pragma unroll
      for (int kcl = 0; kcl < 2; ++kcl)
        b[fc][kcl] = *(const half8*)&Bs[pn][((wcl * 2 + fc) * 2 + kcl) * 512 + lane * 8];
    half8 a0k0, a0k1, a1k0, a1k1;
    frags_of(xa, a0k0, a0k1);
    frags_of(xb, a1k0, a1k1);
    __builtin_amdgcn_s_setprio(1);
    acc[0][0] = __builtin_amdgcn_mfma_f32_32x32x16_f16(a0k0, b[0][0], acc[0][0], 0, 0, 0);
    acc[0][1] = __builtin_amdgcn_mfma_f32_32x32x16_f16(a0k0, b[1][0], acc[0][1], 0, 0, 0);
    acc[1][0] = __builtin_amdgcn_mfma_f32_32x32x16_f16(a1k0, b[0][0], acc[1][0], 0, 0, 0);
    acc[1][1] = __builtin_amdgcn_mfma_f32_32x32x16_f16(a1k0, b[1][0], acc[1][1], 0, 0, 0);
    acc[0][0] = __builtin_amdgcn_mfma_f32_32x32x16_f16(a0k1, b[0][1], acc[0][0], 0, 0, 0);
    acc[0][1] = __builtin_amdgcn_mfma_f32_32x32x16_f16(a0k1, b[1][1], acc[0][1], 0, 0, 0);
    acc[1][0] = __builtin_amdgcn_mfma_f32_32x32x16_f16(a1k1, b[0][1], acc[1][0], 0, 0, 0);
    acc[1][1] = __builtin_amdgcn_mfma_f32_32x32x16_f16(a1k1, b[1][1], acc[1][1], 0, 0, 0);
    __builtin_amdgcn_s_setprio(0);
  };

  // prologue: stage substep 0, load its x
  stage(0, 0);
  float xa = px[0], xb = px[32];
  px += B_ROWS;
  __syncthreads();

#pragma unroll 1
  for (int s = 0; s < 256; s += 2) {
    // phase A: consume buf0 (substep s); stage s+1 into buf1
    stage(1, s + 1);
    const float xa1 = px[0], xb1 = px[32];
    px += B_ROWS;
    compute(0, xa, xb);
    __syncthreads();
    // phase B: consume buf1 (substep s+1); stage s+2 into buf0
    if (s + 2 < 256) {
      stage(0, s + 2);
      xa = px[0]; xb = px[32];
      px += B_ROWS;
    }
    compute(1, xa1, xb1);
    __syncthreads();
  }

  // epilogue: C/D 32x32 layout col=lane&31, row=(q&3)+8*(q>>2)+4*(lane>>5)
  float* dst;
  if (ATOMIC) dst = out;
  else dst = (kb == 0) ? out : part + (size_t)(kb - 1) * (B_ROWS * O_COLS);
#pragma unroll
  for (int fr = 0; fr < 2; ++fr)
#pragma unroll
    for (int fc = 0; fc < 2; ++fc)
#pragma unroll
      for (int q = 0; q < 16; ++q) {
        const int row = m0 + wr * 64 + fr * 32 + (q & 3) + 8 * (q >> 2) + 4 * kh;
        const int col = o0 + wcl * 64 + fc * 32 + r32;
        if (ATOMIC) atomicAdd(&dst[(size_t)row * O_COLS + col], acc[fr][fc][q]);
        else dst[(size_t)row * O_COLS + col] = acc[fr][fc][q];
      }
}

// ---------------------------------------------------------------------------
// Fallback (ws too small): direct-coef 16x16x32 path (no workspace).
// ---------------------------------------------------------------------------
__global__ __launch_bounds__(512, 4)
void fourier_gemm_direct(const float* __restrict__ x, const float* __restrict__ coef,
                         float* __restrict__ out) {
  __shared__ _Float16 Asd[128 * 64];
  __shared__ _Float16 Bsd[128 * 64];

  const int tid = threadIdx.x;
  const int lane = tid & 63;
  const int wave = tid >> 6;
  const int wr = wave >> 1;
  const int wc = wave & 1;

  const int bid = blockIdx.x;
  const int o0 = (bid & 7) * 128;
  const int kb = (bid >> 3) & 1;
  const int m0 = (bid >> 4) * 128;

  const int rowA = tid >> 3;
  const int cch = tid & 7;
  const int cswz = cch ^ (rowA & 7);
  const int n1 = tid >> 3;
  const int c1q = tid & 7;
  const int r16 = lane & 15;
  const int kq = lane >> 4;

  float4v acc[2][4];
#pragma unroll
  for (int fr = 0; fr < 2; ++fr)
#pragma unroll
    for (int fc = 0; fc < 4; ++fc) acc[fr][fc] = (float4v){0.f, 0.f, 0.f, 0.f};

  float s1a[8], c1a[8], sa[8], ca[8];
  float s1b[8], c1b[8], sb[8], cb[8];

  const float* xa_base = x + (size_t)(m0 + rowA) * I_DIM + (size_t)kb * 512 + cch * 8;
  const float* xb_base = xa_base + (size_t)64 * I_DIM;

#pragma unroll 1
  for (int ib2 = 0; ib2 < 8; ++ib2) {
    {
      const float* xa = xa_base + ib2 * 64;
      const float* xb = xb_base + ib2 * 64;
      float xva[8], xvb[8];
      *(float4*)&xva[0] = *(const float4*)(xa);
      *(float4*)&xva[4] = *(const float4*)(xa + 4);
      *(float4*)&xvb[0] = *(const float4*)(xb);
      *(float4*)&xvb[4] = *(const float4*)(xb + 4);
#pragma unroll
      for (int e = 0; e < 8; ++e) {
        __sincosf(xva[e], &s1a[e], &c1a[e]); sa[e] = s1a[e]; ca[e] = c1a[e];
        __sincosf(xvb[e], &s1b[e], &c1b[e]); sb[e] = s1b[e]; cb[e] = c1b[e];
      }
    }
#pragma unroll 1
    for (int f = 0; f < NF33; ++f) {
      H8 ha, hb;
      if (f == 32) {
#pragma unroll
        for (int e = 0; e < 8; ++e) { ha.h[e] = (_Float16)1.0f; hb.h[e] = (_Float16)1.0f; }
      } else if ((f & 1) == 0) {
#pragma unroll
        for (int e = 0; e < 8; ++e) { ha.h[e] = (_Float16)sa[e]; hb.h[e] = (_Float16)sb[e]; }
      } else {
#pragma unroll
        for (int e = 0; e < 8; ++e) { ha.h[e] = (_Float16)ca[e]; hb.h[e] = (_Float16)cb[e]; }
      }
      __syncthreads();
      {
        const int ks = ksrc_of(f);
        const int ibg = kb * 8 + ib2;
        H8 b1, b2;
#pragma unroll
        for (int e = 0; e < 8; ++e) {
          const size_t ii = (size_t)(ibg * 64 + c1q * 8 + e) * NF33 + ks;
          b1.h[e] = (_Float16)coef[(size_t)(o0 + n1) * (I_DIM * NF33) + ii];
          b2.h[e] = (_Float16)coef[(size_t)(o0 + n1 + 64) * (I_DIM * NF33) + ii];
        }
        const int cs = (c1q ^ (n1 & 7)) << 3;
        *(half8*)&Bsd[n1 * 64 + cs] = b1.v;
        *(half8*)&Bsd[(n1 + 64) * 64 + cs] = b2.v;
      }
      *(half8*)&Asd[rowA * 64 + cswz * 8] = ha.v;
      *(half8*)&Asd[(rowA + 64) * 64 + cswz * 8] = hb.v;
      if ((f & 1) && (f + 2 < NF33)) {
#pragma unroll
        for (int e = 0; e < 8; ++e) {
          float ns = sa[e] * c1a[e] + ca[e] * s1a[e];
          ca[e] = ca[e] * c1a[e] - sa[e] * s1a[e]; sa[e] = ns;
          float nsb = sb[e] * c1b[e] + cb[e] * s1b[e];
          cb[e] = cb[e] * c1b[e] - sb[e] * s1b[e]; sb[e] = nsb;
        }
      }
      __syncthreads();
#pragma unroll
      for (int ksu = 0; ksu < 2; ++ksu) {
        const int ch = ((ksu << 2) + kq) ^ (r16 & 7);
        half8 af[2], bf[4];
#pragma unroll
        for (int fr = 0; fr < 2; ++fr)
          af[fr] = *(const half8*)&Asd[(wr * 32 + fr * 16 + r16) * 64 + ch * 8];
#pragma unroll
        for (int fc = 0; fc < 4; ++fc)
          bf[fc] = *(const half8*)&Bsd[(wc * 64 + fc * 16 + r16) * 64 + ch * 8];
#pragma unroll
        for (int fr = 0; fr < 2; ++fr)
#pragma unroll
          for (int fc = 0; fc < 4; ++fc)
            acc[fr][fc] = __builtin_amdgcn_mfma_f32_16x16x32_f16(
                af[fr], bf[fc], acc[fr][fc], 0, 0, 0);
      }
    }
  }
#pragma unroll
  for (int fr = 0; fr < 2; ++fr)
#pragma unroll
    for (int fc = 0; fc < 4; ++fc)
#pragma unroll
      for (int r = 0; r < 4; ++r) {
        const int row = m0 + wr * 32 + fr * 16 + kq * 4 + r;
        const int col = o0 + wc * 64 + fc * 16 + r16;
        atomicAdd(&out[(size_t)row * O_COLS + col], acc[fr][fc][r]);
      }
}

extern "C" void kernel_launch(void* const* d_in, const int* in_sizes, int n_in,
                              void* d_out, int out_size, void* d_ws, size_t ws_size,
                              hipStream_t stream) {
  const float* x = (const float*)d_in[0];
  const float* coef = (const float*)d_in[1];
  float* out = (float*)d_out;

  if (ws_size >= NEED_T1 || ws_size >= NEED_T2) {
    _Float16* Cw2 = (_Float16*)d_ws;
    float* xT   = (float*)((char*)d_ws + XT_OFF);
    float* bk   = (float*)((char*)d_ws + BK_OFF);
    float* bias = (float*)((char*)d_ws + BIAS_OFF);
    convert_coef2<<<dim3(4096), dim3(256), 0, stream>>>(coef, Cw2, bk);
    transpose_x<<<dim3(16, 64), dim3(256), 0, stream>>>(x, xT);
    bias_from_bk<<<dim3(4), dim3(256), 0, stream>>>(bk, bias);
    if (ws_size >= NEED_T1) {
      float* part = (float*)((char*)d_ws + PART_OFF);
      fourier_gemm5<false><<<dim3(512), dim3(512), 0, stream>>>(xT, Cw2, bias, out, part);
      reduce_parts<<<dim3(4096), dim3(256), 0, stream>>>(
          out, part, part + (size_t)B_ROWS * O_COLS, part + (size_t)2 * B_ROWS * O_COLS);
    } else {
      hipMemsetAsync(out, 0, (size_t)B_ROWS * O_COLS * sizeof(float), stream);
      fourier_gemm5<true><<<dim3(512), dim3(512), 0, stream>>>(xT, Cw2, bias, out, nullptr);
    }
  } else {
    hipMemsetAsync(out, 0, (size_t)B_ROWS * O_COLS * sizeof(float), stream);
    fourier_gemm_direct<<<dim3(512), dim3(512), 0, stream>>>(x, coef, out);
  }
}

// Round 8
// 453.884 us; speedup vs baseline: 7.5827x; 1.3119x over previous
//
#include <hip/hip_runtime.h>

// CustomFourierLayer: out[b,o] = sum_{i,k} coef[o,i,k] * f_k(x[b,i])
// R8: batch-phase GEMM. A-frags generated ONCE per block into LDS
// (phase = 2 i-columns, double-buffered, 72B row stride => 2-way-free
// LDS access), one lgkm-only barrier per phase; B frag-blobs direct
// global->VGPR per wave, prefetched 1 substep ahead (loads cross barriers,
// no vmcnt drain). BM=128 BN=256, 4 waves, fr=4 fc=2, split-K x4,
// grid 512 = 2 blocks/CU sharing the same B stream.

#define O_COLS 1024
#define I_DIM  1024
#define NF33   33
#define B_ROWS 4096

#define CW2_BYTES  ((size_t)32 * 2048 * 512 * 2)   // 64 MiB, f16 frag blobs
#define XT_OFF     (CW2_BYTES)                      // 16 MiB f32 x^T
#define XT_BYTES   ((size_t)I_DIM * B_ROWS * 4)
#define BK_OFF     (XT_OFF + XT_BYTES)              // 4 MiB f32 bk32[i][o]
#define BK_BYTES   ((size_t)I_DIM * O_COLS * 4)
#define BIAS_OFF   (BK_OFF + BK_BYTES)              // 4 KiB
#define PART_OFF   (BIAS_OFF + (1 << 20))           // 3 x 16 MiB partials
#define PART_BYTES ((size_t)B_ROWS * O_COLS * 4)
#define NEED_T1    (PART_OFF + 3 * PART_BYTES)
#define NEED_T2    (BIAS_OFF + 4096)

#define ASTR 36    // A LDS row stride in f16 (72 B = 18 dwords; r / r+16 2-way free)

typedef _Float16 half8 __attribute__((ext_vector_type(8)));
typedef float f32x16 __attribute__((ext_vector_type(16)));
typedef float float4v __attribute__((ext_vector_type(4)));
union H8 { half8 v; _Float16 h[8]; };

#define BAR() asm volatile("s_waitcnt lgkmcnt(0)\n\ts_barrier" ::: "memory")

// source k in coef's [sin1..16 | cos1..16 | 1] layout for interleaved feature f
__device__ __forceinline__ int ksrc_of(int f) {
  return (f >= 32) ? 32 : ((f >> 1) + ((f & 1) ? 16 : 0));
}

// ---------------------------------------------------------------------------
// coef f32 [o][i][k] -> Cw2 f16 in 32x32x16 B-fragment blobs + bk32[i][o]=k32.
// Blob (ob32, i*2+kcl) = 1KB: lane l = kh*32 + (o&31) holds 8 f16 = features
// kcl*16 + kh*8 + e of column i, output col o = ob32*32 + (l&31). (validated)
// ---------------------------------------------------------------------------
__global__ __launch_bounds__(256)
void convert_coef2(const float* __restrict__ coef, _Float16* __restrict__ Cw2,
                   float* __restrict__ bk) {
  const int gtid = blockIdx.x * 256 + threadIdx.x;   // 1M threads
  const int o = gtid & 1023;
  const int i = gtid >> 10;

  const float* src = coef + (size_t)o * (I_DIM * NF33) + (size_t)i * NF33;
  float r[NF33];
#pragma unroll
  for (int k = 0; k < NF33; ++k) r[k] = src[k];

  const int ob32 = o >> 5;
#pragma unroll
  for (int kcl = 0; kcl < 2; ++kcl) {
#pragma unroll
    for (int kh = 0; kh < 2; ++kh) {
      H8 h;
#pragma unroll
      for (int e = 0; e < 8; ++e)
        h.h[e] = (_Float16)r[ksrc_of(kcl * 16 + kh * 8 + e)];
      const size_t blob = (size_t)ob32 * 2048 + (size_t)i * 2 + kcl;
      *(half8*)(Cw2 + blob * 512 + (kh * 32 + (o & 31)) * 8) = h.v;
    }
  }
  bk[(size_t)i * 1024 + o] = r[32];
}

// x [4096][1024] -> xT [1024][4096]
__global__ __launch_bounds__(256)
void transpose_x(const float* __restrict__ x, float* __restrict__ xT) {
  __shared__ float t[64][65];
  const int bi = blockIdx.x;   // I-tile 0..15
  const int bj = blockIdx.y;   // B-tile 0..63
  const int tx = threadIdx.x & 63, ty = threadIdx.x >> 6;
#pragma unroll
  for (int mq = 0; mq < 16; ++mq) {
    const int r = mq * 4 + ty;
    t[r][tx] = x[(size_t)(bj * 64 + r) * I_DIM + bi * 64 + tx];
  }
  __syncthreads();
#pragma unroll
  for (int mq = 0; mq < 16; ++mq) {
    const int r = mq * 4 + ty;
    xT[(size_t)(bi * 64 + r) * B_ROWS + bj * 64 + tx] = t[tx][r];
  }
}

// bias[o] = sum_i bk[i][o]
__global__ __launch_bounds__(256)
void bias_from_bk(const float* __restrict__ bk, float* __restrict__ bias) {
  const int o = blockIdx.x * 256 + threadIdx.x;
  float s0 = 0.f, s1 = 0.f, s2 = 0.f, s3 = 0.f;
  for (int i = 0; i < 1024; i += 4) {
    s0 += bk[(size_t)i * 1024 + o];
    s1 += bk[(size_t)(i + 1) * 1024 + o];
    s2 += bk[(size_t)(i + 2) * 1024 + o];
    s3 += bk[(size_t)(i + 3) * 1024 + o];
  }
  bias[o] = (s0 + s1) + (s2 + s3);
}

// out += p0 + p1 + p2
__global__ __launch_bounds__(256)
void reduce_parts(float* __restrict__ out, const float* __restrict__ p0,
                  const float* __restrict__ p1, const float* __restrict__ p2) {
  const size_t i = ((size_t)blockIdx.x * 256 + threadIdx.x) * 4;
  float4v a = *(float4v*)(out + i);
  float4v b = *(const float4v*)(p0 + i);
  float4v c = *(const float4v*)(p1 + i);
  float4v d = *(const float4v*)(p2 + i);
  *(float4v*)(out + i) = a + b + c + d;
}

// ---------------------------------------------------------------------------
// GEMM: 256 threads = 4 waves (wave = col-quarter wc), BM=128, BN=256,
// fr=4 x fc=2, 32x32x16 f16 MFMA. Phase = 2 i-columns; A-frags for the
// phase generated once per block into LDS (dbuf), 1 lgkm barrier/phase.
// ---------------------------------------------------------------------------
template <bool ATOMIC>
__global__ __launch_bounds__(256, 2)
void fourier_gemm6(const float* __restrict__ xT, const _Float16* __restrict__ Cw2,
                   const float* __restrict__ bias, float* __restrict__ out,
                   float* __restrict__ part) {
  __shared__ _Float16 As[2][2][128][ASTR];   // [buf][col][row][36], 36 KB

  const int tid = threadIdx.x, lane = tid & 63, wc = tid >> 6;

  const int bid = blockIdx.x;        // 512 = 16 g x 32 m; co-resident pair shares g
  const int g = bid & 15;
  const int m0 = (bid >> 4) * 128;
  const int n = g >> 2;
  const int kb = g & 3;
  const int o0 = n * 256;
  const int i0 = kb * 256;

  const int r32 = lane & 31, kh = lane >> 5;

  // A-gen assignment: thread owns (row = tid&127, col-in-phase cl = tid>>7)
  const int grow = tid & 127;
  const int gcl = tid >> 7;
  const float* pxg = xT + (size_t)(i0 + gcl) * B_ROWS + (m0 + grow);

  // B pointers: wave covers cols o0 + wc*64 + fc*32
  const _Float16* pb0 = Cw2 + ((size_t)(n * 8 + wc * 2 + 0) * 2048 + (size_t)i0 * 2) * 512 + lane * 8;
  const _Float16* pb1 = Cw2 + ((size_t)(n * 8 + wc * 2 + 1) * 2048 + (size_t)i0 * 2) * 512 + lane * 8;

  f32x16 acc[4][2];
#pragma unroll
  for (int fr = 0; fr < 4; ++fr)
#pragma unroll
    for (int fc = 0; fc < 2; ++fc)
#pragma unroll
      for (int q = 0; q < 16; ++q) acc[fr][fc][q] = 0.f;
  if (kb == 0) {
#pragma unroll
    for (int fc = 0; fc < 2; ++fc) {
      const float bv = bias[o0 + wc * 64 + fc * 32 + r32];
#pragma unroll
      for (int fr = 0; fr < 4; ++fr)
#pragma unroll
        for (int q = 0; q < 16; ++q) acc[fr][fc][q] = bv;
    }
  }

  // generate 32 features (harmonics 1..16, [sin,cos] interleaved) of one
  // (row,col) into LDS buf bn: 1 sincos + 15 rotation steps, 4 ds_write_b128
  auto genA = [&](int bn, float xv) {
    float s1, c1;
    __sincosf(xv, &s1, &c1);
    float s = s1, c = c1;
    _Float16* dst = &As[bn][gcl][grow][0];
#pragma unroll
    for (int c4 = 0; c4 < 4; ++c4) {
      H8 h;
#pragma unroll
      for (int q = 0; q < 4; ++q) {
        h.h[2 * q] = (_Float16)s; h.h[2 * q + 1] = (_Float16)c;
        const float ns = s * c1 + c * s1;
        c = c * c1 - s * s1;
        s = ns;
      }
      *(half8*)(dst + c4 * 8) = h.v;
    }
  };

  auto loadB = [&](half8 (&Bt)[4], int s) {   // s = local substep 0..255(+)
    const size_t base = (size_t)(s * 2) * 512;
    Bt[0] = *(const half8*)(pb0 + base);
    Bt[1] = *(const half8*)(pb0 + base + 512);
    Bt[2] = *(const half8*)(pb1 + base);
    Bt[3] = *(const half8*)(pb1 + base + 512);
  };

  auto compute = [&](int bn, int col, const half8 (&Bt)[4]) {
    half8 a_[4][2];
#pragma unroll
    for (int fr = 0; fr < 4; ++fr)
#pragma unroll
      for (int kcl = 0; kcl < 2; ++kcl)
        a_[fr][kcl] = *(const half8*)&As[bn][col][fr * 32 + r32][(kcl * 2 + kh) * 8];
    __builtin_amdgcn_s_setprio(1);
#pragma unroll
    for (int kcl = 0; kcl < 2; ++kcl)
#pragma unroll
      for (int fr = 0; fr < 4; ++fr)
#pragma unroll
        for (int fc = 0; fc < 2; ++fc)
          acc[fr][fc] = __builtin_amdgcn_mfma_f32_32x32x16_f16(
              a_[fr][kcl], Bt[fc * 2 + kcl], acc[fr][fc], 0, 0, 0);
    __builtin_amdgcn_s_setprio(0);
  };

  half8 B0[4], B1[4];

  // prologue: A for phase 0 into buf0; x for phase 1 gen; B for substep 0
  genA(0, pxg[0]);
  float xg = pxg[(size_t)2 * B_ROWS];     // x for phase-1 gen
  loadB(B0, 0);
  BAR();

#pragma unroll 1
  for (int p = 0; p < 128; ++p) {
    const int buf = p & 1;
    const int s = 2 * p;
    // x for phase p+2 gen (OOB-safe: reads land inside d_ws)
    const float xn = pxg[(size_t)(s + 4) * B_ROWS];

    loadB(B1, s + 1);
    compute(buf, 0, B0);       // substep s
    genA(buf ^ 1, xg);         // A for phase p+1
    loadB(B0, s + 2);          // B for next phase's first substep
    compute(buf, 1, B1);       // substep s+1
    BAR();                     // lgkm-only: B loads stay in flight
    xg = xn;
  }

  // epilogue: C/D 32x32 layout col=lane&31, row=(q&3)+8*(q>>2)+4*(lane>>5)
  float* dst;
  if (ATOMIC) dst = out;
  else dst = (kb == 0) ? out : part + (size_t)(kb - 1) * (B_ROWS * O_COLS);
#pragma unroll
  for (int fr = 0; fr < 4; ++fr)
#pragma unroll
    for (int fc = 0; fc < 2; ++fc)
#pragma unroll
      for (int q = 0; q < 16; ++q) {
        const int row = m0 + fr * 32 + (q & 3) + 8 * (q >> 2) + 4 * kh;
        const int col = o0 + wc * 64 + fc * 32 + r32;
        if (ATOMIC) atomicAdd(&dst[(size_t)row * O_COLS + col], acc[fr][fc][q]);
        else dst[(size_t)row * O_COLS + col] = acc[fr][fc][q];
      }
}

// ---------------------------------------------------------------------------
// Fallback (ws too small): direct-coef 16x16x32 path (no workspace).
// ---------------------------------------------------------------------------
__global__ __launch_bounds__(512, 4)
void fourier_gemm_direct(const float* __restrict__ x, const float* __restrict__ coef,
                         float* __restrict__ out) {
  __shared__ _Float16 Asd[128 * 64];
  __shared__ _Float16 Bsd[128 * 64];

  const int tid = threadIdx.x;
  const int lane = tid & 63;
  const int wave = tid >> 6;
  const int wr = wave >> 1;
  const int wcd = wave & 1;

  const int bid = blockIdx.x;
  const int o0 = (bid & 7) * 128;
  const int kb = (bid >> 3) & 1;
  const int m0 = (bid >> 4) * 128;

  const int rowA = tid >> 3;
  const int cch = tid & 7;
  const int cswz = cch ^ (rowA & 7);
  const int n1 = tid >> 3;
  const int c1q = tid & 7;
  const int r16 = lane & 15;
  const int kq = lane >> 4;

  float4v acc[2][4];
#pragma unroll
  for (int fr = 0; fr < 2; ++fr)
#pragma unroll
    for (int fc = 0; fc < 4; ++fc) acc[fr][fc] = (float4v){0.f, 0.f, 0.f, 0.f};

  float s1a[8], c1a[8], sa[8], ca[8];
  float s1b[8], c1b[8], sb[8], cb[8];

  const float* xa_base = x + (size_t)(m0 + rowA) * I_DIM + (size_t)kb * 512 + cch * 8;
  const float* xb_base = xa_base + (size_t)64 * I_DIM;

#pragma unroll 1
  for (int ib2 = 0; ib2 < 8; ++ib2) {
    {
      const float* xa = xa_base + ib2 * 64;
      const float* xb = xb_base + ib2 * 64;
      float xva[8], xvb[8];
      *(float4*)&xva[0] = *(const float4*)(xa);
      *(float4*)&xva[4] = *(const float4*)(xa + 4);
      *(float4*)&xvb[0] = *(const float4*)(xb);
      *(float4*)&xvb[4] = *(const float4*)(xb + 4);
#pragma unroll
      for (int e = 0; e < 8; ++e) {
        __sincosf(xva[e], &s1a[e], &c1a[e]); sa[e] = s1a[e]; ca[e] = c1a[e];
        __sincosf(xvb[e], &s1b[e], &c1b[e]); sb[e] = s1b[e]; cb[e] = c1b[e];
      }
    }
#pragma unroll 1
    for (int f = 0; f < NF33; ++f) {
      H8 ha, hb;
      if (f == 32) {
#pragma unroll
        for (int e = 0; e < 8; ++e) { ha.h[e] = (_Float16)1.0f; hb.h[e] = (_Float16)1.0f; }
      } else if ((f & 1) == 0) {
#pragma unroll
        for (int e = 0; e < 8; ++e) { ha.h[e] = (_Float16)sa[e]; hb.h[e] = (_Float16)sb[e]; }
      } else {
#pragma unroll
        for (int e = 0; e < 8; ++e) { ha.h[e] = (_Float16)ca[e]; hb.h[e] = (_Float16)cb[e]; }
      }
      __syncthreads();
      {
        const int ks = ksrc_of(f);
        const int ibg = kb * 8 + ib2;
        H8 b1, b2;
#pragma unroll
        for (int e = 0; e < 8; ++e) {
          const size_t ii = (size_t)(ibg * 64 + c1q * 8 + e) * NF33 + ks;
          b1.h[e] = (_Float16)coef[(size_t)(o0 + n1) * (I_DIM * NF33) + ii];
          b2.h[e] = (_Float16)coef[(size_t)(o0 + n1 + 64) * (I_DIM * NF33) + ii];
        }
        const int cs = (c1q ^ (n1 & 7)) << 3;
        *(half8*)&Bsd[n1 * 64 + cs] = b1.v;
        *(half8*)&Bsd[(n1 + 64) * 64 + cs] = b2.v;
      }
      *(half8*)&Asd[rowA * 64 + cswz * 8] = ha.v;
      *(half8*)&Asd[(rowA + 64) * 64 + cswz * 8] = hb.v;
      if ((f & 1) && (f + 2 < NF33)) {
#pragma unroll
        for (int e = 0; e < 8; ++e) {
          float ns = sa[e] * c1a[e] + ca[e] * s1a[e];
          ca[e] = ca[e] * c1a[e] - sa[e] * s1a[e]; sa[e] = ns;
          float nsb = sb[e] * c1b[e] + cb[e] * s1b[e];
          cb[e] = cb[e] * c1b[e] - sb[e] * s1b[e]; sb[e] = nsb;
        }
      }
      __syncthreads();
#pragma unroll
      for (int ksu = 0; ksu < 2; ++ksu) {
        const int ch = ((ksu << 2) + kq) ^ (r16 & 7);
        half8 af[2], bf[4];
#pragma unroll
        for (int fr = 0; fr < 2; ++fr)
          af[fr] = *(const half8*)&Asd[(wr * 32 + fr * 16 + r16) * 64 + ch * 8];
#pragma unroll
        for (int fc = 0; fc < 4; ++fc)
          bf[fc] = *(const half8*)&Bsd[(wcd * 64 + fc * 16 + r16) * 64 + ch * 8];
#pragma unroll
        for (int fr = 0; fr < 2; ++fr)
#pragma unroll
          for (int fc = 0; fc < 4; ++fc)
            acc[fr][fc] = __builtin_amdgcn_mfma_f32_16x16x32_f16(
                af[fr], bf[fc], acc[fr][fc], 0, 0, 0);
      }
    }
  }
#pragma unroll
  for (int fr = 0; fr < 2; ++fr)
#pragma unroll
    for (int fc = 0; fc < 4; ++fc)
#pragma unroll
      for (int r = 0; r < 4; ++r) {
        const int row = m0 + wr * 32 + fr * 16 + kq * 4 + r;
        const int col = o0 + wcd * 64 + fc * 16 + r16;
        atomicAdd(&out[(size_t)row * O_COLS + col], acc[fr][fc][r]);
      }
}

extern "C" void kernel_launch(void* const* d_in, const int* in_sizes, int n_in,
                              void* d_out, int out_size, void* d_ws, size_t ws_size,
                              hipStream_t stream) {
  const float* x = (const float*)d_in[0];
  const float* coef = (const float*)d_in[1];
  float* out = (float*)d_out;

  if (ws_size >= NEED_T1 || ws_size >= NEED_T2) {
    _Float16* Cw2 = (_Float16*)d_ws;
    float* xT   = (float*)((char*)d_ws + XT_OFF);
    float* bk   = (float*)((char*)d_ws + BK_OFF);
    float* bias = (float*)((char*)d_ws + BIAS_OFF);
    convert_coef2<<<dim3(4096), dim3(256), 0, stream>>>(coef, Cw2, bk);
    transpose_x<<<dim3(16, 64), dim3(256), 0, stream>>>(x, xT);
    bias_from_bk<<<dim3(4), dim3(256), 0, stream>>>(bk, bias);
    if (ws_size >= NEED_T1) {
      float* part = (float*)((char*)d_ws + PART_OFF);
      fourier_gemm6<false><<<dim3(512), dim3(256), 0, stream>>>(xT, Cw2, bias, out, part);
      reduce_parts<<<dim3(4096), dim3(256), 0, stream>>>(
          out, part, part + (size_t)B_ROWS * O_COLS, part + (size_t)2 * B_ROWS * O_COLS);
    } else {
      hipMemsetAsync(out, 0, (size_t)B_ROWS * O_COLS * sizeof(float), stream);
      fourier_gemm6<true><<<dim3(512), dim3(256), 0, stream>>>(xT, Cw2, bias, out, nullptr);
    }
  } else {
    hipMemsetAsync(out, 0, (size_t)B_ROWS * O_COLS * sizeof(float), stream);
    fourier_gemm_direct<<<dim3(512), dim3(512), 0, stream>>>(x, coef, out);
  }
}

// Round 9
// 450.241 us; speedup vs baseline: 7.6440x; 1.0081x over previous
//
#include <hip/hip_runtime.h>

// CustomFourierLayer: out[b,o] = sum_{i,k} coef[o,i,k] * f_k(x[b,i])
// R9: phase = 4 i-columns (64 barriers total), doubling-tree harmonic gen
// (depth-4 chain vs serial 15-step rotation), no setprio. A-frags once per
// block into LDS (As[2][4][128][36], 73.7KB, 2 blocks/CU); B frag-blobs
// global->VGPR rolling 1-substep-ahead (loads cross lgkm-only barriers).
// BM=128 BN=256, 4 waves, fr=4 fc=2, 32x32x16 f16 MFMA, split-K x4.

#define O_COLS 1024
#define I_DIM  1024
#define NF33   33
#define B_ROWS 4096

#define CW2_BYTES  ((size_t)32 * 2048 * 512 * 2)   // 64 MiB, f16 frag blobs
#define XT_OFF     (CW2_BYTES)                      // 16 MiB f32 x^T
#define XT_BYTES   ((size_t)I_DIM * B_ROWS * 4)
#define BK_OFF     (XT_OFF + XT_BYTES)              // 4 MiB f32 bk32[i][o]
#define BK_BYTES   ((size_t)I_DIM * O_COLS * 4)
#define BIAS_OFF   (BK_OFF + BK_BYTES)              // 4 KiB
#define PART_OFF   (BIAS_OFF + (1 << 20))           // 3 x 16 MiB partials
#define PART_BYTES ((size_t)B_ROWS * O_COLS * 4)
#define NEED_T1    (PART_OFF + 3 * PART_BYTES)
#define NEED_T2    (BIAS_OFF + 4096)

#define ASTR 36    // A LDS row stride in f16 (72 B; 2-way bank aliasing = free)

typedef _Float16 half8 __attribute__((ext_vector_type(8)));
typedef float f32x16 __attribute__((ext_vector_type(16)));
typedef float float4v __attribute__((ext_vector_type(4)));
union H8 { half8 v; _Float16 h[8]; };

#define BAR() asm volatile("s_waitcnt lgkmcnt(0)\n\ts_barrier" ::: "memory")

// source k in coef's [sin1..16 | cos1..16 | 1] layout for interleaved feature f
__device__ __forceinline__ int ksrc_of(int f) {
  return (f >= 32) ? 32 : ((f >> 1) + ((f & 1) ? 16 : 0));
}

// ---------------------------------------------------------------------------
// coef f32 [o][i][k] -> Cw2 f16 in 32x32x16 B-fragment blobs + bk32[i][o]=k32.
// Blob (ob32, i*2+kcl) = 1KB: lane l = kh*32 + (o&31) holds 8 f16 = features
// kcl*16 + kh*8 + e of column i, output col o = ob32*32 + (l&31). (validated)
// ---------------------------------------------------------------------------
__global__ __launch_bounds__(256)
void convert_coef2(const float* __restrict__ coef, _Float16* __restrict__ Cw2,
                   float* __restrict__ bk) {
  const int gtid = blockIdx.x * 256 + threadIdx.x;   // 1M threads
  const int o = gtid & 1023;
  const int i = gtid >> 10;

  const float* src = coef + (size_t)o * (I_DIM * NF33) + (size_t)i * NF33;
  float r[NF33];
#pragma unroll
  for (int k = 0; k < NF33; ++k) r[k] = src[k];

  const int ob32 = o >> 5;
#pragma unroll
  for (int kcl = 0; kcl < 2; ++kcl) {
#pragma unroll
    for (int kh = 0; kh < 2; ++kh) {
      H8 h;
#pragma unroll
      for (int e = 0; e < 8; ++e)
        h.h[e] = (_Float16)r[ksrc_of(kcl * 16 + kh * 8 + e)];
      const size_t blob = (size_t)ob32 * 2048 + (size_t)i * 2 + kcl;
      *(half8*)(Cw2 + blob * 512 + (kh * 32 + (o & 31)) * 8) = h.v;
    }
  }
  bk[(size_t)i * 1024 + o] = r[32];
}

// x [4096][1024] -> xT [1024][4096]
__global__ __launch_bounds__(256)
void transpose_x(const float* __restrict__ x, float* __restrict__ xT) {
  __shared__ float t[64][65];
  const int bi = blockIdx.x;   // I-tile 0..15
  const int bj = blockIdx.y;   // B-tile 0..63
  const int tx = threadIdx.x & 63, ty = threadIdx.x >> 6;
#pragma unroll
  for (int mq = 0; mq < 16; ++mq) {
    const int r = mq * 4 + ty;
    t[r][tx] = x[(size_t)(bj * 64 + r) * I_DIM + bi * 64 + tx];
  }
  __syncthreads();
#pragma unroll
  for (int mq = 0; mq < 16; ++mq) {
    const int r = mq * 4 + ty;
    xT[(size_t)(bi * 64 + r) * B_ROWS + bj * 64 + tx] = t[tx][r];
  }
}

// bias[o] = sum_i bk[i][o]
__global__ __launch_bounds__(256)
void bias_from_bk(const float* __restrict__ bk, float* __restrict__ bias) {
  const int o = blockIdx.x * 256 + threadIdx.x;
  float s0 = 0.f, s1 = 0.f, s2 = 0.f, s3 = 0.f;
  for (int i = 0; i < 1024; i += 4) {
    s0 += bk[(size_t)i * 1024 + o];
    s1 += bk[(size_t)(i + 1) * 1024 + o];
    s2 += bk[(size_t)(i + 2) * 1024 + o];
    s3 += bk[(size_t)(i + 3) * 1024 + o];
  }
  bias[o] = (s0 + s1) + (s2 + s3);
}

// out += p0 + p1 + p2
__global__ __launch_bounds__(256)
void reduce_parts(float* __restrict__ out, const float* __restrict__ p0,
                  const float* __restrict__ p1, const float* __restrict__ p2) {
  const size_t i = ((size_t)blockIdx.x * 256 + threadIdx.x) * 4;
  float4v a = *(float4v*)(out + i);
  float4v b = *(const float4v*)(p0 + i);
  float4v c = *(const float4v*)(p1 + i);
  float4v d = *(const float4v*)(p2 + i);
  *(float4v*)(out + i) = a + b + c + d;
}

// ---------------------------------------------------------------------------
// GEMM: 256 threads = 4 waves (wave = col-quarter wc), BM=128, BN=256,
// fr=4 x fc=2, 32x32x16 f16 MFMA. Phase = 4 i-columns; A-frags generated
// once per block into LDS (dbuf), ONE lgkm-only barrier per phase.
// ---------------------------------------------------------------------------
template <bool ATOMIC>
__global__ __launch_bounds__(256, 2)
void fourier_gemm7(const float* __restrict__ xT, const _Float16* __restrict__ Cw2,
                   const float* __restrict__ bias, float* __restrict__ out,
                   float* __restrict__ part) {
  __shared__ _Float16 As[2][4][128][ASTR];   // [buf][col][row][36], 73.7 KB

  const int tid = threadIdx.x, lane = tid & 63, wc = tid >> 6;

  const int bid = blockIdx.x;        // 512 = 16 g x 32 m; co-resident pair shares g
  const int g = bid & 15;
  const int m0 = (bid >> 4) * 128;
  const int n = g >> 2;
  const int kb = g & 3;
  const int o0 = n * 256;
  const int i0 = kb * 256;

  const int r32 = lane & 31, kh = lane >> 5;

  // A-gen assignment: thread owns row grow, cols {gcw, gcw+2} of each phase
  const int grow = tid & 127;
  const int gcw = tid >> 7;          // 0 or 1
  const float* pxa = xT + (size_t)(i0 + gcw) * B_ROWS + (m0 + grow);
  const float* pxb = pxa + (size_t)2 * B_ROWS;

  // B pointers: wave covers cols o0 + wc*64 + fc*32
  const _Float16* pb0 = Cw2 + ((size_t)(n * 8 + wc * 2 + 0) * 2048 + (size_t)i0 * 2) * 512 + lane * 8;
  const _Float16* pb1 = Cw2 + ((size_t)(n * 8 + wc * 2 + 1) * 2048 + (size_t)i0 * 2) * 512 + lane * 8;

  f32x16 acc[4][2];
#pragma unroll
  for (int fr = 0; fr < 4; ++fr)
#pragma unroll
    for (int fc = 0; fc < 2; ++fc)
#pragma unroll
      for (int q = 0; q < 16; ++q) acc[fr][fc][q] = 0.f;
  if (kb == 0) {
#pragma unroll
    for (int fc = 0; fc < 2; ++fc) {
      const float bv = bias[o0 + wc * 64 + fc * 32 + r32];
#pragma unroll
      for (int fr = 0; fr < 4; ++fr)
#pragma unroll
        for (int q = 0; q < 16; ++q) acc[fr][fc][q] = bv;
    }
  }

  // doubling-tree harmonics 1..16 of xv -> 32 interleaved [sin,cos] f16 at dst
  // (chunk c4 = harmonics 4c4+1..4c4+4; depth-4 dependency chain)
  auto genH = [&](float xv, _Float16* dst) {
    float S[17], C[17];
    __sincosf(xv, &S[1], &C[1]);
    S[2] = 2.f * S[1] * C[1];  C[2] = fmaf(-2.f * S[1], S[1], 1.f);
    S[3] = S[2] * C[1] + C[2] * S[1];  C[3] = C[2] * C[1] - S[2] * S[1];
    S[4] = 2.f * S[2] * C[2];  C[4] = fmaf(-2.f * S[2], S[2], 1.f);
    S[5] = S[4] * C[1] + C[4] * S[1];  C[5] = C[4] * C[1] - S[4] * S[1];
    S[6] = S[4] * C[2] + C[4] * S[2];  C[6] = C[4] * C[2] - S[4] * S[2];
    S[7] = S[4] * C[3] + C[4] * S[3];  C[7] = C[4] * C[3] - S[4] * S[3];
    S[8] = 2.f * S[4] * C[4];  C[8] = fmaf(-2.f * S[4], S[4], 1.f);
#pragma unroll
    for (int k = 1; k < 8; ++k) {
      S[8 + k] = S[8] * C[k] + C[8] * S[k];
      C[8 + k] = C[8] * C[k] - S[8] * S[k];
    }
    S[16] = 2.f * S[8] * C[8];  C[16] = fmaf(-2.f * S[8], S[8], 1.f);
#pragma unroll
    for (int c4 = 0; c4 < 4; ++c4) {
      H8 h;
#pragma unroll
      for (int q = 0; q < 4; ++q) {
        const int k = c4 * 4 + q + 1;
        h.h[2 * q] = (_Float16)S[k];  h.h[2 * q + 1] = (_Float16)C[k];
      }
      *(half8*)(dst + c4 * 8) = h.v;
    }
  };

  half8 B0[4], B1[4];
  auto loadB = [&](half8 (&Bt)[4], int s) {   // s = local substep index
    const size_t base = (size_t)(s * 2) * 512;
    Bt[0] = *(const half8*)(pb0 + base);
    Bt[1] = *(const half8*)(pb0 + base + 512);
    Bt[2] = *(const half8*)(pb1 + base);
    Bt[3] = *(const half8*)(pb1 + base + 512);
  };

  auto compute = [&](int bn, int col, const half8 (&Bt)[4]) {
    half8 a_[4][2];
#pragma unroll
    for (int fr = 0; fr < 4; ++fr)
#pragma unroll
      for (int kcl = 0; kcl < 2; ++kcl)
        a_[fr][kcl] = *(const half8*)&As[bn][col][fr * 32 + r32][(kcl * 2 + kh) * 8];
#pragma unroll
    for (int kcl = 0; kcl < 2; ++kcl)
#pragma unroll
      for (int fr = 0; fr < 4; ++fr)
#pragma unroll
        for (int fc = 0; fc < 2; ++fc)
          acc[fr][fc] = __builtin_amdgcn_mfma_f32_32x32x16_f16(
              a_[fr][kcl], Bt[fc * 2 + kcl], acc[fr][fc], 0, 0, 0);
  };

  // prologue: A for phase 0 into buf0; x for phase 1; B for substep 0
  {
    const float xa0 = pxa[0], xb0 = pxb[0];
    genH(xa0, &As[0][gcw][grow][0]);
    genH(xb0, &As[0][gcw + 2][grow][0]);
  }
  float xa = pxa[(size_t)4 * B_ROWS], xb = pxb[(size_t)4 * B_ROWS];
  loadB(B0, 0);
  BAR();

#pragma unroll 1
  for (int p = 0; p < 64; ++p) {
    const int buf = p & 1;
    const int s = 4 * p;
    // x for phase p+2 (OOB-safe: worst case lands in bk region inside d_ws)
    const float xan = pxa[(size_t)(s + 8) * B_ROWS];
    const float xbn = pxb[(size_t)(s + 8) * B_ROWS];

    loadB(B1, s + 1);
    compute(buf, 0, B0);
    loadB(B0, s + 2);
    compute(buf, 1, B1);
    loadB(B1, s + 3);
    compute(buf, 2, B0);
    if (p < 63) loadB(B0, s + 4);
    genH(xa, &As[buf ^ 1][gcw][grow][0]);       // A for phase p+1
    genH(xb, &As[buf ^ 1][gcw + 2][grow][0]);
    compute(buf, 3, B1);
    BAR();                     // lgkm-only: B global loads stay in flight
    xa = xan; xb = xbn;
  }

  // epilogue: C/D 32x32 layout col=lane&31, row=(q&3)+8*(q>>2)+4*(lane>>5)
  float* dst;
  if (ATOMIC) dst = out;
  else dst = (kb == 0) ? out : part + (size_t)(kb - 1) * (B_ROWS * O_COLS);
#pragma unroll
  for (int fr = 0; fr < 4; ++fr)
#pragma unroll
    for (int fc = 0; fc < 2; ++fc)
#pragma unroll
      for (int q = 0; q < 16; ++q) {
        const int row = m0 + fr * 32 + (q & 3) + 8 * (q >> 2) + 4 * kh;
        const int col = o0 + wc * 64 + fc * 32 + r32;
        if (ATOMIC) atomicAdd(&dst[(size_t)row * O_COLS + col], acc[fr][fc][q]);
        else dst[(size_t)row * O_COLS + col] = acc[fr][fc][q];
      }
}

// ---------------------------------------------------------------------------
// Fallback (ws too small): direct-coef 16x16x32 path (no workspace).
// ---------------------------------------------------------------------------
__global__ __launch_bounds__(512, 4)
void fourier_gemm_direct(const float* __restrict__ x, const float* __restrict__ coef,
                         float* __restrict__ out) {
  __shared__ _Float16 Asd[128 * 64];
  __shared__ _Float16 Bsd[128 * 64];

  const int tid = threadIdx.x;
  const int lane = tid & 63;
  const int wave = tid >> 6;
  const int wr = wave >> 1;
  const int wcd = wave & 1;

  const int bid = blockIdx.x;
  const int o0 = (bid & 7) * 128;
  const int kb = (bid >> 3) & 1;
  const int m0 = (bid >> 4) * 128;

  const int rowA = tid >> 3;
  const int cch = tid & 7;
  const int cswz = cch ^ (rowA & 7);
  const int n1 = tid >> 3;
  const int c1q = tid & 7;
  const int r16 = lane & 15;
  const int kq = lane >> 4;

  float4v acc[2][4];
#pragma unroll
  for (int fr = 0; fr < 2; ++fr)
#pragma unroll
    for (int fc = 0; fc < 4; ++fc) acc[fr][fc] = (float4v){0.f, 0.f, 0.f, 0.f};

  float s1a[8], c1a[8], sa[8], ca[8];
  float s1b[8], c1b[8], sb[8], cb[8];

  const float* xa_base = x + (size_t)(m0 + rowA) * I_DIM + (size_t)kb * 512 + cch * 8;
  const float* xb_base = xa_base + (size_t)64 * I_DIM;

#pragma unroll 1
  for (int ib2 = 0; ib2 < 8; ++ib2) {
    {
      const float* xa = xa_base + ib2 * 64;
      const float* xb = xb_base + ib2 * 64;
      float xva[8], xvb[8];
      *(float4*)&xva[0] = *(const float4*)(xa);
      *(float4*)&xva[4] = *(const float4*)(xa + 4);
      *(float4*)&xvb[0] = *(const float4*)(xb);
      *(float4*)&xvb[4] = *(const float4*)(xb + 4);
#pragma unroll
      for (int e = 0; e < 8; ++e) {
        __sincosf(xva[e], &s1a[e], &c1a[e]); sa[e] = s1a[e]; ca[e] = c1a[e];
        __sincosf(xvb[e], &s1b[e], &c1b[e]); sb[e] = s1b[e]; cb[e] = c1b[e];
      }
    }
#pragma unroll 1
    for (int f = 0; f < NF33; ++f) {
      H8 ha, hb;
      if (f == 32) {
#pragma unroll
        for (int e = 0; e < 8; ++e) { ha.h[e] = (_Float16)1.0f; hb.h[e] = (_Float16)1.0f; }
      } else if ((f & 1) == 0) {
#pragma unroll
        for (int e = 0; e < 8; ++e) { ha.h[e] = (_Float16)sa[e]; hb.h[e] = (_Float16)sb[e]; }
      } else {
#pragma unroll
        for (int e = 0; e < 8; ++e) { ha.h[e] = (_Float16)ca[e]; hb.h[e] = (_Float16)cb[e]; }
      }
      __syncthreads();
      {
        const int ks = ksrc_of(f);
        const int ibg = kb * 8 + ib2;
        H8 b1, b2;
#pragma unroll
        for (int e = 0; e < 8; ++e) {
          const size_t ii = (size_t)(ibg * 64 + c1q * 8 + e) * NF33 + ks;
          b1.h[e] = (_Float16)coef[(size_t)(o0 + n1) * (I_DIM * NF33) + ii];
          b2.h[e] = (_Float16)coef[(size_t)(o0 + n1 + 64) * (I_DIM * NF33) + ii];
        }
        const int cs = (c1q ^ (n1 & 7)) << 3;
        *(half8*)&Bsd[n1 * 64 + cs] = b1.v;
        *(half8*)&Bsd[(n1 + 64) * 64 + cs] = b2.v;
      }
      *(half8*)&Asd[rowA * 64 + cswz * 8] = ha.v;
      *(half8*)&Asd[(rowA + 64) * 64 + cswz * 8] = hb.v;
      if ((f & 1) && (f + 2 < NF33)) {
#pragma unroll
        for (int e = 0; e < 8; ++e) {
          float ns = sa[e] * c1a[e] + ca[e] * s1a[e];
          ca[e] = ca[e] * c1a[e] - sa[e] * s1a[e]; sa[e] = ns;
          float nsb = sb[e] * c1b[e] + cb[e] * s1b[e];
          cb[e] = cb[e] * c1b[e] - sb[e] * s1b[e]; sb[e] = nsb;
        }
      }
      __syncthreads();
#pragma unroll
      for (int ksu = 0; ksu < 2; ++ksu) {
        const int ch = ((ksu << 2) + kq) ^ (r16 & 7);
        half8 af[2], bf[4];
#pragma unroll
        for (int fr = 0; fr < 2; ++fr)
          af[fr] = *(const half8*)&Asd[(wr * 32 + fr * 16 + r16) * 64 + ch * 8];
#pragma unroll
        for (int fc = 0; fc < 4; ++fc)
          bf[fc] = *(const half8*)&Bsd[(wcd * 64 + fc * 16 + r16) * 64 + ch * 8];
#pragma unroll
        for (int fr = 0; fr < 2; ++fr)
#pragma unroll
          for (int fc = 0; fc < 4; ++fc)
            acc[fr][fc] = __builtin_amdgcn_mfma_f32_16x16x32_f16(
                af[fr], bf[fc], acc[fr][fc], 0, 0, 0);
      }
    }
  }
#pragma unroll
  for (int fr = 0; fr < 2; ++fr)
#pragma unroll
    for (int fc = 0; fc < 4; ++fc)
#pragma unroll
      for (int r = 0; r < 4; ++r) {
        const int row = m0 + wr * 32 + fr * 16 + kq * 4 + r;
        const int col = o0 + wcd * 64 + fc * 16 + r16;
        atomicAdd(&out[(size_t)row * O_COLS + col], acc[fr][fc][r]);
      }
}

extern "C" void kernel_launch(void* const* d_in, const int* in_sizes, int n_in,
                              void* d_out, int out_size, void* d_ws, size_t ws_size,
                              hipStream_t stream) {
  const float* x = (const float*)d_in[0];
  const float* coef = (const float*)d_in[1];
  float* out = (float*)d_out;

  if (ws_size >= NEED_T1 || ws_size >= NEED_T2) {
    _Float16* Cw2 = (_Float16*)d_ws;
    float* xT   = (float*)((char*)d_ws + XT_OFF);
    float* bk   = (float*)((char*)d_ws + BK_OFF);
    float* bias = (float*)((char*)d_ws + BIAS_OFF);
    convert_coef2<<<dim3(4096), dim3(256), 0, stream>>>(coef, Cw2, bk);
    transpose_x<<<dim3(16, 64), dim3(256), 0, stream>>>(x, xT);
    bias_from_bk<<<dim3(4), dim3(256), 0, stream>>>(bk, bias);
    if (ws_size >= NEED_T1) {
      float* part = (float*)((char*)d_ws + PART_OFF);
      fourier_gemm7<false><<<dim3(512), dim3(256), 0, stream>>>(xT, Cw2, bias, out, part);
      reduce_parts<<<dim3(4096), dim3(256), 0, stream>>>(
          out, part, part + (size_t)B_ROWS * O_COLS, part + (size_t)2 * B_ROWS * O_COLS);
    } else {
      hipMemsetAsync(out, 0, (size_t)B_ROWS * O_COLS * sizeof(float), stream);
      fourier_gemm7<true><<<dim3(512), dim3(256), 0, stream>>>(xT, Cw2, bias, out, nullptr);
    }
  } else {
    hipMemsetAsync(out, 0, (size_t)B_ROWS * O_COLS * sizeof(float), stream);
    fourier_gemm_direct<<<dim3(512), dim3(512), 0, stream>>>(x, coef, out);
  }
}